// Round 1
// baseline (1464.711 us; speedup 1.0000x reference)
//
#include <hip/hip_runtime.h>
#include <math.h>

#define N_NODES   100000
#define N_EDGES   1600000
#define N_FEAT    64
#define HIDDEN    64
#define BIOPRINT  2048
#define N_GRAPHS  1024

// ---------------- degree / normalization ----------------

__global__ void k_deg(const int* __restrict__ dst, int* __restrict__ deg, int n) {
    int i = blockIdx.x * blockDim.x + threadIdx.x;
    if (i < n) atomicAdd(&deg[dst[i]], 1);
}

__global__ void k_dinv(const int* __restrict__ deg, float* __restrict__ dinv, int n) {
    int i = blockIdx.x * blockDim.x + threadIdx.x;
    if (i < n) dinv[i] = rsqrtf((float)deg[i] + 1.0f);
}

// ---------------- h @ W  (+ fused self-loop init of agg) ----------------
// Each block: 4 rows x 64 cols, 256 threads, W staged in LDS.
// Writes hw[i][j] = (relu(h) @ W)[i][j]
//        agg[i][j] = hw[i][j] * dinv[i]^2 + b[j]   (self-loop + bias init)
__global__ __launch_bounds__(256) void k_mm(
        const float* __restrict__ h, const float* __restrict__ W,
        const float* __restrict__ b, const float* __restrict__ dinv,
        float* __restrict__ hw, float* __restrict__ agg, int relu_in) {
    __shared__ float sW[64 * 64];
    __shared__ float sH[4 * 64];
    int t = threadIdx.x;
    for (int i = t; i < 64 * 64; i += 256) sW[i] = W[i];
    int row0 = blockIdx.x * 4;
    {
        int r = t >> 6, j = t & 63;
        float v = h[(row0 + r) * 64 + j];
        if (relu_in) v = fmaxf(v, 0.0f);
        sH[r * 64 + j] = v;
    }
    __syncthreads();
    int r = t >> 6, j = t & 63;
    int i = row0 + r;
    float sum = 0.0f;
#pragma unroll
    for (int k = 0; k < 64; ++k) sum = fmaf(sH[r * 64 + k], sW[k * 64 + j], sum);
    float di = dinv[i];
    hw[i * 64 + j] = sum;
    agg[i * 64 + j] = sum * di * di + b[j];
}

// ---------------- edge scatter: agg[dst] += hw[src] * dinv[src]*dinv[dst] ----------------
// One wave (64 lanes) per edge -> broadcast index loads, coalesced 256B gather/atomics.
__global__ __launch_bounds__(256) void k_scatter(
        const int* __restrict__ src, const int* __restrict__ dst,
        const float* __restrict__ dinv, const float* __restrict__ hw,
        float* __restrict__ agg) {
    int gid = blockIdx.x * 256 + threadIdx.x;
    int e = gid >> 6;
    int f = gid & 63;
    int s = src[e];
    int d = dst[e];
    float w = dinv[s] * dinv[d];
    atomicAdd(&agg[d * 64 + f], hw[s * 64 + f] * w);
}

// ---------------- pooling ----------------

__global__ void k_cnt(const int* __restrict__ batch, float* __restrict__ cnt, int n) {
    int i = blockIdx.x * blockDim.x + threadIdx.x;
    if (i < n) atomicAdd(&cnt[batch[i]], 1.0f);
}

__global__ __launch_bounds__(256) void k_pool(
        const int* __restrict__ batch, const float* __restrict__ h,
        float* __restrict__ pooled) {
    int gid = blockIdx.x * 256 + threadIdx.x;
    int i = gid >> 6;
    int f = gid & 63;
    atomicAdd(&pooled[batch[i] * 64 + f], h[i * 64 + f]);
}

// ---------------- dense + softmax + threshold ----------------
// One block per graph; 256 threads x 8 logits each = 2048.
__global__ __launch_bounds__(256) void k_dense(
        const float* __restrict__ pooled, const float* __restrict__ cnt,
        const float* __restrict__ Wd, const float* __restrict__ bd,
        float* __restrict__ out) {
    __shared__ float sp[64];
    __shared__ float smax[4];
    __shared__ float ssum[4];
    int g = blockIdx.x, t = threadIdx.x;
    if (t < 64) {
        float c = cnt[g];
        sp[t] = pooled[g * 64 + t] / fmaxf(c, 1.0f);
    }
    __syncthreads();
    float l[8];
#pragma unroll
    for (int r = 0; r < 8; ++r) {
        int c = r * 256 + t;
        float s = bd[c];
#pragma unroll
        for (int k = 0; k < 64; ++k) s = fmaf(sp[k], Wd[k * BIOPRINT + c], s);
        l[r] = s;
    }
    // block max
    float m = l[0];
#pragma unroll
    for (int r = 1; r < 8; ++r) m = fmaxf(m, l[r]);
#pragma unroll
    for (int off = 32; off > 0; off >>= 1) m = fmaxf(m, __shfl_xor(m, off));
    if ((t & 63) == 0) smax[t >> 6] = m;
    __syncthreads();
    m = fmaxf(fmaxf(smax[0], smax[1]), fmaxf(smax[2], smax[3]));
    // sum of exp
    float e[8];
    float sum = 0.0f;
#pragma unroll
    for (int r = 0; r < 8; ++r) { e[r] = expf(l[r] - m); sum += e[r]; }
#pragma unroll
    for (int off = 32; off > 0; off >>= 1) sum += __shfl_xor(sum, off);
    if ((t & 63) == 0) ssum[t >> 6] = sum;
    __syncthreads();
    sum = ssum[0] + ssum[1] + ssum[2] + ssum[3];
#pragma unroll
    for (int r = 0; r < 8; ++r) {
        float p = e[r] / sum;
        out[g * BIOPRINT + r * 256 + t] = (p >= 0.5f) ? 1.0f : 0.0f;
    }
}

// ---------------- launch ----------------

extern "C" void kernel_launch(void* const* d_in, const int* in_sizes, int n_in,
                              void* d_out, int out_size, void* d_ws, size_t ws_size,
                              hipStream_t stream) {
    const float* x     = (const float*)d_in[0];
    const int*   ei    = (const int*)d_in[1];      // [2][N_EDGES]: src, dst
    const int*   batch = (const int*)d_in[2];
    const float* W1 = (const float*)d_in[3];
    const float* b1 = (const float*)d_in[4];
    const float* W2 = (const float*)d_in[5];
    const float* b2 = (const float*)d_in[6];
    const float* W3 = (const float*)d_in[7];
    const float* b3 = (const float*)d_in[8];
    const float* Wd = (const float*)d_in[9];
    const float* bd = (const float*)d_in[10];
    float* out = (float*)d_out;

    const int* src = ei;
    const int* dst = ei + N_EDGES;

    char* ws = (char*)d_ws;
    size_t off = 0;
    auto alloc = [&](size_t bytes) {
        void* p = ws + off;
        off += (bytes + 255) & ~(size_t)255;
        return p;
    };
    int*   deg    = (int*)alloc(N_NODES * sizeof(int));
    float* dinv   = (float*)alloc(N_NODES * sizeof(float));
    float* pooled = (float*)alloc(N_GRAPHS * HIDDEN * sizeof(float));
    float* cnt    = (float*)alloc(N_GRAPHS * sizeof(float));
    float* buf0   = (float*)alloc((size_t)N_NODES * HIDDEN * sizeof(float));
    float* buf1   = (float*)alloc((size_t)N_NODES * HIDDEN * sizeof(float));
    float* buf2   = (float*)alloc((size_t)N_NODES * HIDDEN * sizeof(float));

    hipMemsetAsync(deg, 0, N_NODES * sizeof(int), stream);
    hipMemsetAsync(pooled, 0, N_GRAPHS * HIDDEN * sizeof(float), stream);
    hipMemsetAsync(cnt, 0, N_GRAPHS * sizeof(float), stream);

    k_deg<<<(N_EDGES + 255) / 256, 256, 0, stream>>>(dst, deg, N_EDGES);
    k_dinv<<<(N_NODES + 255) / 256, 256, 0, stream>>>(deg, dinv, N_NODES);

    const int mm_grid = N_NODES / 4;            // 25000 (100000 % 4 == 0)
    const int sc_grid = N_EDGES * 64 / 256;     // 400000
    // layer 1: h = x        -> hw buf0, agg buf1
    k_mm<<<mm_grid, 256, 0, stream>>>(x, W1, b1, dinv, buf0, buf1, 0);
    k_scatter<<<sc_grid, 256, 0, stream>>>(src, dst, dinv, buf0, buf1);
    // layer 2: h = buf1(relu) -> hw buf2, agg buf0
    k_mm<<<mm_grid, 256, 0, stream>>>(buf1, W2, b2, dinv, buf2, buf0, 1);
    k_scatter<<<sc_grid, 256, 0, stream>>>(src, dst, dinv, buf2, buf0);
    // layer 3: h = buf0(relu) -> hw buf1, agg buf2
    k_mm<<<mm_grid, 256, 0, stream>>>(buf0, W3, b3, dinv, buf1, buf2, 1);
    k_scatter<<<sc_grid, 256, 0, stream>>>(src, dst, dinv, buf1, buf2);
    // pool (h_final = buf2)
    k_cnt<<<(N_NODES + 255) / 256, 256, 0, stream>>>(batch, cnt, N_NODES);
    k_pool<<<N_NODES * 64 / 256, 256, 0, stream>>>(batch, buf2, pooled);
    // dense + softmax + threshold
    k_dense<<<N_GRAPHS, 256, 0, stream>>>(pooled, cnt, Wd, bd, out);
}

// Round 2
// 828.373 us; speedup vs baseline: 1.7682x; 1.7682x over previous
//
#include <hip/hip_runtime.h>
#include <math.h>

#define N_NODES   100000
#define N_EDGES   1600000
#define N_FEAT    64
#define HIDDEN    64
#define BIOPRINT  2048
#define N_GRAPHS  1024

#define SCAN_BLK  1024
#define N_SCAN_BLOCKS ((N_NODES + SCAN_BLK - 1) / SCAN_BLK)   // 98

// ---------------- degree / normalization ----------------

__global__ void k_deg(const int* __restrict__ dst, int* __restrict__ deg, int n) {
    int i = blockIdx.x * blockDim.x + threadIdx.x;
    if (i < n) atomicAdd(&deg[dst[i]], 1);
}

__global__ void k_dinv(const int* __restrict__ deg, float* __restrict__ dinv, int n) {
    int i = blockIdx.x * blockDim.x + threadIdx.x;
    if (i < n) dinv[i] = rsqrtf((float)deg[i] + 1.0f);
}

// ---------------- CSR build: scan of degrees ----------------
// scan1: per-block inclusive scan of deg -> rowptr (temp, inclusive), block sums -> bsum
__global__ __launch_bounds__(SCAN_BLK) void k_scan1(
        const int* __restrict__ deg, int* __restrict__ incl,
        int* __restrict__ bsum, int n) {
    __shared__ int tmp[SCAN_BLK];
    int t = threadIdx.x;
    int i = blockIdx.x * SCAN_BLK + t;
    int v = (i < n) ? deg[i] : 0;
    tmp[t] = v;
    __syncthreads();
    for (int off = 1; off < SCAN_BLK; off <<= 1) {
        int u = (t >= off) ? tmp[t - off] : 0;
        __syncthreads();
        tmp[t] += u;
        __syncthreads();
    }
    if (i < n) incl[i] = tmp[t];
    if (t == SCAN_BLK - 1) bsum[blockIdx.x] = tmp[t];
}

// scan2: serial exclusive scan of 98 block sums (trivial)
__global__ void k_scan2(int* __restrict__ bsum, int nb) {
    if (threadIdx.x == 0 && blockIdx.x == 0) {
        int run = 0;
        for (int b = 0; b < nb; ++b) { int v = bsum[b]; bsum[b] = run; run += v; }
    }
}

// scan3: rowptr[i] = incl[i] - deg[i] + bsum[blk]  (exclusive); cursor = rowptr copy
__global__ __launch_bounds__(SCAN_BLK) void k_scan3(
        int* __restrict__ rowptr, const int* __restrict__ deg,
        const int* __restrict__ bsum, int* __restrict__ cursor, int n) {
    int i = blockIdx.x * SCAN_BLK + threadIdx.x;
    if (i < n) {
        int ex = rowptr[i] - deg[i] + bsum[blockIdx.x];
        rowptr[i] = ex;
        cursor[i] = ex;
    }
    if (i == 0) rowptr[n] = N_EDGES;
}

// fill: place each edge in its dst's CSR slot; precompute edge weight
__global__ void k_fill(const int* __restrict__ src, const int* __restrict__ dst,
                       const float* __restrict__ dinv, int* __restrict__ cursor,
                       int* __restrict__ col, float* __restrict__ wgt, int n) {
    int e = blockIdx.x * blockDim.x + threadIdx.x;
    if (e < n) {
        int s = src[e], d = dst[e];
        int pos = atomicAdd(&cursor[d], 1);
        col[pos] = s;
        wgt[pos] = dinv[s] * dinv[d];
    }
}

// ---------------- h @ W ----------------
// Each block: 4 rows x 64 cols, 256 threads, W staged in LDS.
__global__ __launch_bounds__(256) void k_mm(
        const float* __restrict__ h, const float* __restrict__ W,
        float* __restrict__ hw, int relu_in) {
    __shared__ float sW[64 * 64];
    __shared__ float sH[4 * 64];
    int t = threadIdx.x;
    for (int i = t; i < 64 * 64; i += 256) sW[i] = W[i];
    int row0 = blockIdx.x * 4;
    {
        int r = t >> 6, j = t & 63;
        float v = h[(row0 + r) * 64 + j];
        if (relu_in) v = fmaxf(v, 0.0f);
        sH[r * 64 + j] = v;
    }
    __syncthreads();
    int r = t >> 6, j = t & 63;
    float sum = 0.0f;
#pragma unroll
    for (int k = 0; k < 64; ++k) sum = fmaf(sH[r * 64 + k], sW[k * 64 + j], sum);
    hw[(row0 + r) * 64 + j] = sum;
}

// ---------------- CSR gather: out[i] = hw[i]*dinv[i]^2 + b + sum_e hw[col[e]]*wgt[e] ----------------
// One wave (64 lanes = 64 features) per node. No atomics.
__global__ __launch_bounds__(256) void k_gather(
        const int* __restrict__ rowptr, const int* __restrict__ col,
        const float* __restrict__ wgt, const float* __restrict__ dinv,
        const float* __restrict__ b, const float* __restrict__ hw,
        float* __restrict__ out) {
    int gid = blockIdx.x * 256 + threadIdx.x;
    int i = gid >> 6;
    int f = gid & 63;
    float di = dinv[i];
    float acc = hw[i * 64 + f] * di * di + b[f];
    int rs = rowptr[i], re = rowptr[i + 1];
    int e = rs;
    // 2-edge unroll for load-level parallelism
    for (; e + 1 < re; e += 2) {
        int   s0 = col[e],     s1 = col[e + 1];
        float w0 = wgt[e],     w1 = wgt[e + 1];
        float v0 = hw[s0 * 64 + f];
        float v1 = hw[s1 * 64 + f];
        acc = fmaf(v0, w0, acc);
        acc = fmaf(v1, w1, acc);
    }
    if (e < re) acc = fmaf(hw[col[e] * 64 + f], wgt[e], acc);
    out[i * 64 + f] = acc;
}

// ---------------- pooling ----------------

__global__ void k_cnt(const int* __restrict__ batch, float* __restrict__ cnt, int n) {
    int i = blockIdx.x * blockDim.x + threadIdx.x;
    if (i < n) atomicAdd(&cnt[batch[i]], 1.0f);
}

__global__ __launch_bounds__(256) void k_pool(
        const int* __restrict__ batch, const float* __restrict__ h,
        float* __restrict__ pooled) {
    int gid = blockIdx.x * 256 + threadIdx.x;
    int i = gid >> 6;
    int f = gid & 63;
    atomicAdd(&pooled[batch[i] * 64 + f], h[i * 64 + f]);
}

// ---------------- dense + softmax + threshold ----------------

__global__ __launch_bounds__(256) void k_dense(
        const float* __restrict__ pooled, const float* __restrict__ cnt,
        const float* __restrict__ Wd, const float* __restrict__ bd,
        float* __restrict__ out) {
    __shared__ float sp[64];
    __shared__ float smax[4];
    __shared__ float ssum[4];
    int g = blockIdx.x, t = threadIdx.x;
    if (t < 64) {
        float c = cnt[g];
        sp[t] = pooled[g * 64 + t] / fmaxf(c, 1.0f);
    }
    __syncthreads();
    float l[8];
#pragma unroll
    for (int r = 0; r < 8; ++r) {
        int c = r * 256 + t;
        float s = bd[c];
#pragma unroll
        for (int k = 0; k < 64; ++k) s = fmaf(sp[k], Wd[k * BIOPRINT + c], s);
        l[r] = s;
    }
    float m = l[0];
#pragma unroll
    for (int r = 1; r < 8; ++r) m = fmaxf(m, l[r]);
#pragma unroll
    for (int off = 32; off > 0; off >>= 1) m = fmaxf(m, __shfl_xor(m, off));
    if ((t & 63) == 0) smax[t >> 6] = m;
    __syncthreads();
    m = fmaxf(fmaxf(smax[0], smax[1]), fmaxf(smax[2], smax[3]));
    float e[8];
    float sum = 0.0f;
#pragma unroll
    for (int r = 0; r < 8; ++r) { e[r] = expf(l[r] - m); sum += e[r]; }
#pragma unroll
    for (int off = 32; off > 0; off >>= 1) sum += __shfl_xor(sum, off);
    if ((t & 63) == 0) ssum[t >> 6] = sum;
    __syncthreads();
    sum = ssum[0] + ssum[1] + ssum[2] + ssum[3];
#pragma unroll
    for (int r = 0; r < 8; ++r) {
        float p = e[r] / sum;
        out[g * BIOPRINT + r * 256 + t] = (p >= 0.5f) ? 1.0f : 0.0f;
    }
}

// ---------------- launch ----------------

extern "C" void kernel_launch(void* const* d_in, const int* in_sizes, int n_in,
                              void* d_out, int out_size, void* d_ws, size_t ws_size,
                              hipStream_t stream) {
    const float* x     = (const float*)d_in[0];
    const int*   ei    = (const int*)d_in[1];      // [2][N_EDGES]: src, dst
    const int*   batch = (const int*)d_in[2];
    const float* W1 = (const float*)d_in[3];
    const float* b1 = (const float*)d_in[4];
    const float* W2 = (const float*)d_in[5];
    const float* b2 = (const float*)d_in[6];
    const float* W3 = (const float*)d_in[7];
    const float* b3 = (const float*)d_in[8];
    const float* Wd = (const float*)d_in[9];
    const float* bd = (const float*)d_in[10];
    float* out = (float*)d_out;

    const int* src = ei;
    const int* dst = ei + N_EDGES;

    char* ws = (char*)d_ws;
    size_t off = 0;
    auto alloc = [&](size_t bytes) {
        void* p = ws + off;
        off += (bytes + 255) & ~(size_t)255;
        return p;
    };
    int*   deg    = (int*)alloc(N_NODES * sizeof(int));
    float* dinv   = (float*)alloc(N_NODES * sizeof(float));
    float* pooled = (float*)alloc(N_GRAPHS * HIDDEN * sizeof(float));
    float* cnt    = (float*)alloc(N_GRAPHS * sizeof(float));
    int*   rowptr = (int*)alloc((N_NODES + 1) * sizeof(int));
    int*   bsum   = (int*)alloc(N_SCAN_BLOCKS * sizeof(int));
    int*   cursor = (int*)alloc(N_NODES * sizeof(int));
    int*   col    = (int*)alloc((size_t)N_EDGES * sizeof(int));
    float* wgt    = (float*)alloc((size_t)N_EDGES * sizeof(float));
    float* bufA   = (float*)alloc((size_t)N_NODES * HIDDEN * sizeof(float));
    float* bufB   = (float*)alloc((size_t)N_NODES * HIDDEN * sizeof(float));
    float* bufC   = (float*)alloc((size_t)N_NODES * HIDDEN * sizeof(float));

    hipMemsetAsync(deg, 0, N_NODES * sizeof(int), stream);
    hipMemsetAsync(pooled, 0, N_GRAPHS * HIDDEN * sizeof(float), stream);
    hipMemsetAsync(cnt, 0, N_GRAPHS * sizeof(float), stream);

    // degrees + normalization
    k_deg<<<(N_EDGES + 255) / 256, 256, 0, stream>>>(dst, deg, N_EDGES);
    k_dinv<<<(N_NODES + 255) / 256, 256, 0, stream>>>(deg, dinv, N_NODES);

    // CSR build (once; reused by all 3 layers)
    k_scan1<<<N_SCAN_BLOCKS, SCAN_BLK, 0, stream>>>(deg, rowptr, bsum, N_NODES);
    k_scan2<<<1, 64, 0, stream>>>(bsum, N_SCAN_BLOCKS);
    k_scan3<<<N_SCAN_BLOCKS, SCAN_BLK, 0, stream>>>(rowptr, deg, bsum, cursor, N_NODES);
    k_fill<<<(N_EDGES + 255) / 256, 256, 0, stream>>>(src, dst, dinv, cursor, col, wgt, N_EDGES);

    const int mm_grid = N_NODES / 4;          // 25000
    const int ga_grid = N_NODES * 64 / 256;   // 25000
    // layer 1: mm(x) -> A; gather(A) -> B
    k_mm<<<mm_grid, 256, 0, stream>>>(x, W1, bufA, 0);
    k_gather<<<ga_grid, 256, 0, stream>>>(rowptr, col, wgt, dinv, b1, bufA, bufB);
    // layer 2: mm(relu B) -> C; gather(C) -> A
    k_mm<<<mm_grid, 256, 0, stream>>>(bufB, W2, bufC, 1);
    k_gather<<<ga_grid, 256, 0, stream>>>(rowptr, col, wgt, dinv, b2, bufC, bufA);
    // layer 3: mm(relu A) -> B; gather(B) -> C
    k_mm<<<mm_grid, 256, 0, stream>>>(bufA, W3, bufB, 1);
    k_gather<<<ga_grid, 256, 0, stream>>>(rowptr, col, wgt, dinv, b3, bufB, bufC);
    // pool (h_final = C)
    k_cnt<<<(N_NODES + 255) / 256, 256, 0, stream>>>(batch, cnt, N_NODES);
    k_pool<<<N_NODES * 64 / 256, 256, 0, stream>>>(batch, bufC, pooled);
    // dense + softmax + threshold
    k_dense<<<N_GRAPHS, 256, 0, stream>>>(pooled, cnt, Wd, bd, out);
}

// Round 3
// 673.792 us; speedup vs baseline: 2.1738x; 1.2294x over previous
//
#include <hip/hip_runtime.h>
#include <math.h>

#define N_NODES   100000
#define N_EDGES   1600000
#define N_FEAT    64
#define HIDDEN    64
#define BIOPRINT  2048
#define N_GRAPHS  1024

#define SCAN_BLK  1024
#define N_SCAN_BLOCKS ((N_NODES + SCAN_BLK - 1) / SCAN_BLK)   // 98

// ---------------- degree / normalization ----------------

__global__ void k_deg(const int* __restrict__ dst, int* __restrict__ deg, int n) {
    int i = blockIdx.x * blockDim.x + threadIdx.x;
    if (i < n) atomicAdd(&deg[dst[i]], 1);
}

// dinv + graph-size count fused (same grid shape)
__global__ void k_dinv_cnt(const int* __restrict__ deg, float* __restrict__ dinv,
                           const int* __restrict__ batch, float* __restrict__ cnt, int n) {
    int i = blockIdx.x * blockDim.x + threadIdx.x;
    if (i < n) {
        dinv[i] = rsqrtf((float)deg[i] + 1.0f);
        atomicAdd(&cnt[batch[i]], 1.0f);
    }
}

// ---------------- CSR build ----------------

__global__ __launch_bounds__(SCAN_BLK) void k_scan1(
        const int* __restrict__ deg, int* __restrict__ incl,
        int* __restrict__ bsum, int n) {
    __shared__ int tmp[SCAN_BLK];
    int t = threadIdx.x;
    int i = blockIdx.x * SCAN_BLK + t;
    int v = (i < n) ? deg[i] : 0;
    tmp[t] = v;
    __syncthreads();
    for (int off = 1; off < SCAN_BLK; off <<= 1) {
        int u = (t >= off) ? tmp[t - off] : 0;
        __syncthreads();
        tmp[t] += u;
        __syncthreads();
    }
    if (i < n) incl[i] = tmp[t];
    if (t == SCAN_BLK - 1) bsum[blockIdx.x] = tmp[t];
}

__global__ void k_scan2(int* __restrict__ bsum, int nb) {
    if (threadIdx.x == 0 && blockIdx.x == 0) {
        int run = 0;
        for (int b = 0; b < nb; ++b) { int v = bsum[b]; bsum[b] = run; run += v; }
    }
}

__global__ __launch_bounds__(SCAN_BLK) void k_scan3(
        int* __restrict__ rowptr, const int* __restrict__ deg,
        const int* __restrict__ bsum, int* __restrict__ cursor, int n) {
    int i = blockIdx.x * SCAN_BLK + threadIdx.x;
    if (i < n) {
        int ex = rowptr[i] - deg[i] + bsum[blockIdx.x];
        rowptr[i] = ex;
        cursor[i] = ex;
    }
    if (i == 0) rowptr[n] = N_EDGES;
}

// fill: one packed 8B store per edge (col index + fp32 weight bits)
__global__ void k_fill(const int* __restrict__ src, const int* __restrict__ dst,
                       const float* __restrict__ dinv, int* __restrict__ cursor,
                       int2* __restrict__ colw, int n) {
    int e = blockIdx.x * blockDim.x + threadIdx.x;
    if (e < n) {
        int s = src[e], d = dst[e];
        int pos = atomicAdd(&cursor[d], 1);
        float w = dinv[s] * dinv[d];
        colw[pos] = make_int2(s, __float_as_int(w));
    }
}

// ---------------- layer-1 matmul: hw = x @ W ----------------
__global__ __launch_bounds__(256) void k_mm(
        const float* __restrict__ h, const float* __restrict__ W,
        float* __restrict__ hw) {
    __shared__ float sW[64 * 64];
    __shared__ float sH[4 * 64];
    int t = threadIdx.x;
    const float4* W4 = (const float4*)W;
    float4* sW4 = (float4*)sW;
    for (int i = t; i < 1024; i += 256) sW4[i] = W4[i];
    int row0 = blockIdx.x * 4;
    {
        int r = t >> 6, j = t & 63;
        sH[r * 64 + j] = h[(row0 + r) * 64 + j];
    }
    __syncthreads();
    int r = t >> 6, j = t & 63;
    float sum = 0.0f;
#pragma unroll
    for (int k = 0; k < 64; ++k) sum = fmaf(sH[r * 64 + k], sW[k * 64 + j], sum);
    hw[(row0 + r) * 64 + j] = sum;
}

// ---------------- fused gather + relu + next-layer matmul ----------------
// Block = 256 threads = 4 waves = 4 nodes. Wave r gathers node i's conv row
// (agg + self + bias) into registers, relu, stage in LDS, then 4x64 @ 64x64 mm.
__global__ __launch_bounds__(256) void k_gmm(
        const int* __restrict__ rowptr, const int2* __restrict__ colw,
        const float* __restrict__ dinv, const float* __restrict__ b,
        const float* __restrict__ hw_in, const float* __restrict__ W,
        float* __restrict__ hw_out) {
    __shared__ float sW[64 * 64];
    __shared__ float sA[4 * 64];
    int t = threadIdx.x;
    const float4* W4 = (const float4*)W;
    float4* sW4 = (float4*)sW;
    for (int i = t; i < 1024; i += 256) sW4[i] = W4[i];

    int wave = t >> 6, f = t & 63;
    int i = blockIdx.x * 4 + wave;
    float di = dinv[i];
    float acc = hw_in[i * 64 + f] * di * di + b[f];
    int rs = rowptr[i], re = rowptr[i + 1];
    int e = rs;
    for (; e + 3 < re; e += 4) {
        int2 c0 = colw[e], c1 = colw[e + 1], c2 = colw[e + 2], c3 = colw[e + 3];
        float v0 = hw_in[c0.x * 64 + f];
        float v1 = hw_in[c1.x * 64 + f];
        float v2 = hw_in[c2.x * 64 + f];
        float v3 = hw_in[c3.x * 64 + f];
        acc = fmaf(v0, __int_as_float(c0.y), acc);
        acc = fmaf(v1, __int_as_float(c1.y), acc);
        acc = fmaf(v2, __int_as_float(c2.y), acc);
        acc = fmaf(v3, __int_as_float(c3.y), acc);
    }
    for (; e < re; ++e) {
        int2 c = colw[e];
        acc = fmaf(hw_in[c.x * 64 + f], __int_as_float(c.y), acc);
    }
    sA[wave * 64 + f] = fmaxf(acc, 0.0f);   // relu before next matmul
    __syncthreads();
    int r = t >> 6, j = t & 63;
    float sum = 0.0f;
#pragma unroll
    for (int k = 0; k < 64; ++k) sum = fmaf(sA[r * 64 + k], sW[k * 64 + j], sum);
    hw_out[(blockIdx.x * 4 + r) * 64 + j] = sum;
}

// ---------------- fused gather (layer 3, no relu) + mean-pool atomics ----------------
__global__ __launch_bounds__(256) void k_gpool(
        const int* __restrict__ rowptr, const int2* __restrict__ colw,
        const float* __restrict__ dinv, const float* __restrict__ b,
        const float* __restrict__ hw_in, const int* __restrict__ batch,
        float* __restrict__ pooled) {
    int gid = blockIdx.x * 256 + threadIdx.x;
    int i = gid >> 6;
    int f = gid & 63;
    float di = dinv[i];
    float acc = hw_in[i * 64 + f] * di * di + b[f];
    int rs = rowptr[i], re = rowptr[i + 1];
    int e = rs;
    for (; e + 3 < re; e += 4) {
        int2 c0 = colw[e], c1 = colw[e + 1], c2 = colw[e + 2], c3 = colw[e + 3];
        float v0 = hw_in[c0.x * 64 + f];
        float v1 = hw_in[c1.x * 64 + f];
        float v2 = hw_in[c2.x * 64 + f];
        float v3 = hw_in[c3.x * 64 + f];
        acc = fmaf(v0, __int_as_float(c0.y), acc);
        acc = fmaf(v1, __int_as_float(c1.y), acc);
        acc = fmaf(v2, __int_as_float(c2.y), acc);
        acc = fmaf(v3, __int_as_float(c3.y), acc);
    }
    for (; e < re; ++e) {
        int2 c = colw[e];
        acc = fmaf(hw_in[c.x * 64 + f], __int_as_float(c.y), acc);
    }
    atomicAdd(&pooled[batch[i] * 64 + f], acc);
}

// ---------------- dense + softmax + threshold ----------------
__global__ __launch_bounds__(256) void k_dense(
        const float* __restrict__ pooled, const float* __restrict__ cnt,
        const float* __restrict__ Wd, const float* __restrict__ bd,
        float* __restrict__ out) {
    __shared__ float sp[64];
    __shared__ float smax[4];
    __shared__ float ssum[4];
    int g = blockIdx.x, t = threadIdx.x;
    if (t < 64) {
        float c = cnt[g];
        sp[t] = pooled[g * 64 + t] / fmaxf(c, 1.0f);
    }
    __syncthreads();
    float l[8];
#pragma unroll
    for (int r = 0; r < 8; ++r) {
        int c = r * 256 + t;
        float s = bd[c];
#pragma unroll
        for (int k = 0; k < 64; ++k) s = fmaf(sp[k], Wd[k * BIOPRINT + c], s);
        l[r] = s;
    }
    float m = l[0];
#pragma unroll
    for (int r = 1; r < 8; ++r) m = fmaxf(m, l[r]);
#pragma unroll
    for (int off = 32; off > 0; off >>= 1) m = fmaxf(m, __shfl_xor(m, off));
    if ((t & 63) == 0) smax[t >> 6] = m;
    __syncthreads();
    m = fmaxf(fmaxf(smax[0], smax[1]), fmaxf(smax[2], smax[3]));
    float e[8];
    float sum = 0.0f;
#pragma unroll
    for (int r = 0; r < 8; ++r) { e[r] = expf(l[r] - m); sum += e[r]; }
#pragma unroll
    for (int off = 32; off > 0; off >>= 1) sum += __shfl_xor(sum, off);
    if ((t & 63) == 0) ssum[t >> 6] = sum;
    __syncthreads();
    sum = ssum[0] + ssum[1] + ssum[2] + ssum[3];
#pragma unroll
    for (int r = 0; r < 8; ++r) {
        float p = e[r] / sum;
        out[g * BIOPRINT + r * 256 + t] = (p >= 0.5f) ? 1.0f : 0.0f;
    }
}

// ---------------- launch ----------------

extern "C" void kernel_launch(void* const* d_in, const int* in_sizes, int n_in,
                              void* d_out, int out_size, void* d_ws, size_t ws_size,
                              hipStream_t stream) {
    const float* x     = (const float*)d_in[0];
    const int*   ei    = (const int*)d_in[1];      // [2][N_EDGES]: src, dst
    const int*   batch = (const int*)d_in[2];
    const float* W1 = (const float*)d_in[3];
    const float* b1 = (const float*)d_in[4];
    const float* W2 = (const float*)d_in[5];
    const float* b2 = (const float*)d_in[6];
    const float* W3 = (const float*)d_in[7];
    const float* b3 = (const float*)d_in[8];
    const float* Wd = (const float*)d_in[9];
    const float* bd = (const float*)d_in[10];
    float* out = (float*)d_out;

    const int* src = ei;
    const int* dst = ei + N_EDGES;

    char* ws = (char*)d_ws;
    size_t off = 0;
    auto alloc = [&](size_t bytes) {
        void* p = ws + off;
        off += (bytes + 255) & ~(size_t)255;
        return p;
    };
    int*   deg    = (int*)alloc(N_NODES * sizeof(int));
    float* dinv   = (float*)alloc(N_NODES * sizeof(float));
    float* pooled = (float*)alloc(N_GRAPHS * HIDDEN * sizeof(float));
    float* cnt    = (float*)alloc(N_GRAPHS * sizeof(float));
    int*   rowptr = (int*)alloc((N_NODES + 1) * sizeof(int));
    int*   bsum   = (int*)alloc(N_SCAN_BLOCKS * sizeof(int));
    int*   cursor = (int*)alloc(N_NODES * sizeof(int));
    int2*  colw   = (int2*)alloc((size_t)N_EDGES * sizeof(int2));
    float* bufA   = (float*)alloc((size_t)N_NODES * HIDDEN * sizeof(float));
    float* bufB   = (float*)alloc((size_t)N_NODES * HIDDEN * sizeof(float));

    hipMemsetAsync(deg, 0, N_NODES * sizeof(int), stream);
    hipMemsetAsync(pooled, 0, N_GRAPHS * HIDDEN * sizeof(float), stream);
    hipMemsetAsync(cnt, 0, N_GRAPHS * sizeof(float), stream);

    k_deg<<<(N_EDGES + 255) / 256, 256, 0, stream>>>(dst, deg, N_EDGES);
    k_dinv_cnt<<<(N_NODES + 255) / 256, 256, 0, stream>>>(deg, dinv, batch, cnt, N_NODES);

    k_scan1<<<N_SCAN_BLOCKS, SCAN_BLK, 0, stream>>>(deg, rowptr, bsum, N_NODES);
    k_scan2<<<1, 64, 0, stream>>>(bsum, N_SCAN_BLOCKS);
    k_scan3<<<N_SCAN_BLOCKS, SCAN_BLK, 0, stream>>>(rowptr, deg, bsum, cursor, N_NODES);
    k_fill<<<(N_EDGES + 255) / 256, 256, 0, stream>>>(src, dst, dinv, cursor, colw, N_EDGES);

    const int mm_grid = N_NODES / 4;          // 25000
    // layer 1 matmul: hw1 = x @ W1 -> A
    k_mm<<<mm_grid, 256, 0, stream>>>(x, W1, bufA);
    // gather conv1 + relu + @W2 -> B
    k_gmm<<<mm_grid, 256, 0, stream>>>(rowptr, colw, dinv, b1, bufA, W2, bufB);
    // gather conv2 + relu + @W3 -> A
    k_gmm<<<mm_grid, 256, 0, stream>>>(rowptr, colw, dinv, b2, bufB, W3, bufA);
    // gather conv3 (no relu) + mean-pool atomics
    k_gpool<<<mm_grid, 256, 0, stream>>>(rowptr, colw, dinv, b3, bufA, batch, pooled);
    // dense + softmax + threshold
    k_dense<<<N_GRAPHS, 256, 0, stream>>>(pooled, cnt, Wd, bd, out);
}